// Round 9
// baseline (106.628 us; speedup 1.0000x reference)
//
#include <hip/hip_runtime.h>

#define N_B    4
#define M_PTS  8192
#define K_PTS  8192
#define CCHUNK 2048               // cols per block (per col-chunk)
#define NTILE  (CCHUNK / 32)      // 64 col-tiles per wave sweep

// Schraudolph exp2: e = bitcast(int(EXPA - FS*d)), validated R4-R8
#define FS    (7.21347520444481703f * 8388608.0f)
#define EXPA  1064879260.0f       // (127 - 0.0565)*2^23, zero-mean rel err
#define SQB   0x1FBD1DF5u         // bit sqrt: d~ = bitcast((bits(s)>>1)+SQB)
#define LN2   0.69314718055994531f

typedef _Float16 f16x8 __attribute__((ext_vector_type(8)));
typedef float    f32x16 __attribute__((ext_vector_type(16)));

__device__ __forceinline__ f16x8 mk_b(uint2 v) {
    union { uint4 u; f16x8 h; } w;
    w.u = make_uint4(v.x, v.y, 0u, 0u);   // k=0..3 payload, k=4..7 zero
    return w.h;
}

// post-process one 32x32 s-tile: e = exp(-ALPHA*sqrt(s)) via bit-sqrt +
// Schraudolph; rows accumulate into rs[16] regs, col partial into LDS.
__device__ __forceinline__ void post_tile(const f32x16& acc, int tpcol,
                                          float* rs, float* col_acc, int lane)
{
    float e[16];
    #pragma unroll
    for (int r = 0; r < 16; ++r) {
        const float s = fmaxf(acc[r], 0.0f);         // f16 cancellation guard
        const unsigned hb = (__float_as_uint(s) >> 1) + SQB;
        const float u = fmaf(__uint_as_float(hb), -FS, EXPA);
        e[r] = __uint_as_float((unsigned)(int)u);
        rs[r] += e[r];
    }
    const float c0 = ((e[0]+e[1])+(e[2]+e[3])) + ((e[4]+e[5])+(e[6]+e[7]));
    const float c1 = ((e[8]+e[9])+(e[10]+e[11])) + ((e[12]+e[13])+(e[14]+e[15]));
    atomicAdd(&col_acc[tpcol * 32 + (lane & 31)], c0 + c1);  // 2-way/addr
}

// R8 lesson: ~20-instr/pair VALU stream is the floor -> move the distance to
// MFMA: s = Np + Ng - 2 p.g as A=[-2px,-2py,Np,1] x B=[gx,gy,1,Ng] (f16,
// K=4 of 16). One mfma_f32_32x32x16_f16 = 1024 s values; VALU only does
// exp post-processing (~15 cyc/64 pairs vs 27 measured in R8).
__global__ __launch_bounds__(256, 4) void softhaus_pair(
    const float* __restrict__ pred, const float* __restrict__ gt,
    float* __restrict__ row_sum, float* __restrict__ col_sum)
{
    __shared__ uint2 bfr[CCHUNK + 32];   // B-frags + 32-entry zero pad
    __shared__ float col_acc[CCHUNK];

    const int n    = blockIdx.z;
    const int rb   = blockIdx.x;          // row-block (128 rows)
    const int cc   = blockIdx.y;          // col-chunk (2048 cols)
    const int tid  = threadIdx.x;
    const int lane = tid & 63;
    const int wv   = tid >> 6;
    const int l31  = lane & 31;

    const float2* P = (const float2*)pred + (size_t)n * M_PTS;
    const float2* G = (const float2*)gt   + (size_t)n * K_PTS;
    const int cbase = cc * CCHUNK;

    // stage B-frags [gx, gy, 1, Ng] (f16x4) for this block's 2048 cols
    for (int i = tid; i < CCHUNK; i += 256) {
        const float2 g = G[cbase + i];
        const float ng = fmaf(g.x, g.x, g.y * g.y);
        union { _Float16 h[4]; uint2 u; } w;
        w.h[0] = (_Float16)g.x; w.h[1] = (_Float16)g.y;
        w.h[2] = (_Float16)1.0f; w.h[3] = (_Float16)ng;
        bfr[i] = w.u;
        col_acc[i] = 0.0f;
    }
    if (tid < 32) bfr[CCHUNK + tid] = make_uint2(0u, 0u);

    // A-frag: wave's 32 rows, [-2px, -2py, Np, 1] in k=0..3 (lanes<32)
    const int wrow0 = rb * 128 + wv * 32;
    const float2 p = P[wrow0 + l31];
    f16x8 a = {};
    if (lane < 32) {
        a[0] = (_Float16)(-2.0f * p.x);
        a[1] = (_Float16)(-2.0f * p.y);
        a[2] = (_Float16)fmaf(p.x, p.x, p.y * p.y);
        a[3] = (_Float16)1.0f;
    }

    __syncthreads();

    float rs[16];
    #pragma unroll
    for (int r = 0; r < 16; ++r) rs[r] = 0.0f;

    // per-lane LDS read pattern: lanes<32 walk the tiles, lanes>=32 read pad
    const unsigned bstride = (lane < 32) ? 32u : 0u;
    const unsigned bbase   = (lane < 32) ? (unsigned)l31
                                         : (unsigned)(CCHUNK + l31);
    const int toff = wv << 4;   // stagger waves' tile order (ds_add spread)
    const f32x16 zacc = {};

    const int tp0 = toff & (NTILE - 1);
    uint2 bvA = bfr[bbase + (unsigned)tp0 * bstride];
    f32x16 accA = __builtin_amdgcn_mfma_f32_32x32x16_f16(a, mk_b(bvA), zacc, 0, 0, 0);

    for (int t = 0; t < NTILE; t += 2) {
        const int tpA = (t     + toff) & (NTILE - 1);
        const int tpB = (t + 1 + toff) & (NTILE - 1);
        // issue next tile's MFMA before post-processing current (hide latency)
        uint2 bvB = bfr[bbase + (unsigned)tpB * bstride];
        f32x16 accB = __builtin_amdgcn_mfma_f32_32x32x16_f16(a, mk_b(bvB), zacc, 0, 0, 0);
        post_tile(accA, tpA, rs, col_acc, lane);

        const int t2  = (t + 2 < NTILE) ? t + 2 : 0;    // last prefetch dummy
        const int tpN = (t2 + toff) & (NTILE - 1);
        uint2 bvN = bfr[bbase + (unsigned)tpN * bstride];
        accA = __builtin_amdgcn_mfma_f32_32x32x16_f16(a, mk_b(bvN), zacc, 0, 0, 0);
        post_tile(accB, tpB, rs, col_acc, lane);
    }

    // row sums: reduce rs over the 32-lane half (each reg = one row)
    #pragma unroll
    for (int r = 0; r < 16; ++r) {
        #pragma unroll
        for (int m = 1; m <= 16; m <<= 1)
            rs[r] += __shfl_xor(rs[r], m, 32);
    }
    if (l31 == 0) {                       // lanes 0 and 32
        const int half4 = (lane >> 5) << 2;
        float* rsum = row_sum + (size_t)n * M_PTS;
        #pragma unroll
        for (int r = 0; r < 16; ++r) {
            const int row = wrow0 + (r & 3) + ((r >> 2) << 3) + half4;
            atomicAdd(&rsum[row], rs[r]);  // 4 writers/addr (col-chunks)
        }
    }

    __syncthreads();
    for (int i = tid; i < CCHUNK; i += 256)
        atomicAdd(&col_sum[(size_t)n * K_PTS + cbase + i], col_acc[i]);
}

// ws: row_sum (N*M) then col_sum (N*K); equal counts -> single 1/(N*M) scale.
__global__ __launch_bounds__(256) void softhaus_finalize(
    const float* __restrict__ sums, float* __restrict__ out)
{
    const int total  = N_B * M_PTS + N_B * K_PTS;
    const int idx    = blockIdx.x * blockDim.x + threadIdx.x;
    const int stride = gridDim.x * blockDim.x;

    float acc = 0.0f;
    for (int i = idx; i < total; i += stride)
        acc -= __builtin_amdgcn_logf(sums[i]) * LN2;   // -log(v)

    #pragma unroll
    for (int off = 32; off > 0; off >>= 1)
        acc += __shfl_down(acc, off);

    __shared__ float wsum[4];
    const int lane = threadIdx.x & 63;
    const int wv   = threadIdx.x >> 6;
    if (lane == 0) wsum[wv] = acc;
    __syncthreads();
    if (threadIdx.x == 0) {
        float b = wsum[0] + wsum[1] + wsum[2] + wsum[3];
        atomicAdd(out, b * (1.0f / (N_B * M_PTS)));
    }
}

extern "C" void kernel_launch(void* const* d_in, const int* in_sizes, int n_in,
                              void* d_out, int out_size, void* d_ws, size_t ws_size,
                              hipStream_t stream) {
    const float* pred = (const float*)d_in[0];
    const float* gt   = (const float*)d_in[1];
    float* ws = (float*)d_ws;

    const size_t acc_bytes = (size_t)(N_B * M_PTS + N_B * K_PTS) * sizeof(float);
    hipMemsetAsync(d_ws, 0, acc_bytes, stream);
    hipMemsetAsync(d_out, 0, sizeof(float), stream);

    dim3 grid(M_PTS / 128, K_PTS / CCHUNK, N_B);   // 64 x 4 x 4 = 1024 blocks
    softhaus_pair<<<grid, 256, 0, stream>>>(pred, gt, ws, ws + (size_t)N_B * M_PTS);
    softhaus_finalize<<<64, 256, 0, stream>>>(ws, (float*)d_out);
}

// Round 10
// 75.429 us; speedup vs baseline: 1.4136x; 1.4136x over previous
//
#include <hip/hip_runtime.h>

#define N_B    4
#define M_PTS  8192
#define K_PTS  8192
#define CCHUNK 1024               // cols per block
#define NTILE  (CCHUNK / 32)      // 32 col-tiles per wave sweep

// Schraudolph exp2: e = bitcast(int(EXPA - FS*d)), validated R4-R9
#define FS    (7.21347520444481703f * 8388608.0f)
#define EXPA  1064879260.0f       // (127 - 0.0565)*2^23, zero-mean rel err
#define SQB   0x1FBD1DF5u         // bit sqrt: d~ = bitcast((bits(s)>>1)+SQB)
#define LN2   0.69314718055994531f

typedef _Float16 f16x8 __attribute__((ext_vector_type(8)));
typedef float    f32x16 __attribute__((ext_vector_type(16)));

__device__ __forceinline__ f16x8 mk_b(uint2 v) {
    union { uint4 u; f16x8 h; } w;
    w.u = make_uint4(v.x, v.y, 0u, 0u);   // k=0..3 payload, k=4..7 zero
    return w.h;
}

// R9 post-mortem: algorithm right (absmax=0, ~15 cyc/64 pairs counted) but
// VGPR=40 => AGPR shuttling + 50% VALU idle. R10: single acc, post in groups
// of 4 (small live range), CCHUNK=1024 (12.4KB LDS), 6+ waves/SIMD, and
// shfl_xor(32) so only 32 lanes issue the per-tile ds_add.
__global__ __launch_bounds__(256, 6) void softhaus_pair(
    const float* __restrict__ pred, const float* __restrict__ gt,
    float* __restrict__ row_sum, float* __restrict__ col_sum)
{
    __shared__ uint2 bfr[CCHUNK + 32];   // B-frags + 32-entry zero pad
    __shared__ float col_acc[CCHUNK];

    const int n    = blockIdx.z;
    const int rb   = blockIdx.x;          // row-block (128 rows)
    const int cc   = blockIdx.y;          // col-chunk (1024 cols)
    const int tid  = threadIdx.x;
    const int lane = tid & 63;
    const int wv   = tid >> 6;
    const int l31  = lane & 31;

    const float2* P = (const float2*)pred + (size_t)n * M_PTS;
    const float2* G = (const float2*)gt   + (size_t)n * K_PTS;
    const int cbase = cc * CCHUNK;

    // stage B-frags [gx, gy, 1, Ng] (f16x4) for this block's cols
    for (int i = tid; i < CCHUNK; i += 256) {
        const float2 g = G[cbase + i];
        const float ng = fmaf(g.x, g.x, g.y * g.y);
        union { _Float16 h[4]; uint2 u; } w;
        w.h[0] = (_Float16)g.x; w.h[1] = (_Float16)g.y;
        w.h[2] = (_Float16)1.0f; w.h[3] = (_Float16)ng;
        bfr[i] = w.u;
    }
    for (int i = tid; i < CCHUNK; i += 256) col_acc[i] = 0.0f;
    if (tid < 32) bfr[CCHUNK + tid] = make_uint2(0u, 0u);

    // A-frag: wave's 32 rows, [-2px, -2py, Np, 1] in k=0..3 (lanes<32 only;
    // lanes>=32 carry k=8..15 which must be zero)
    const int wrow0 = rb * 128 + wv * 32;
    const float2 p = P[wrow0 + l31];
    f16x8 a = {};
    if (lane < 32) {
        a[0] = (_Float16)(-2.0f * p.x);
        a[1] = (_Float16)(-2.0f * p.y);
        a[2] = (_Float16)fmaf(p.x, p.x, p.y * p.y);
        a[3] = (_Float16)1.0f;
    }

    __syncthreads();

    float rs[16];
    #pragma unroll
    for (int r = 0; r < 16; ++r) rs[r] = 0.0f;

    // lanes<32 walk the tiles, lanes>=32 read the zero pad
    const unsigned bstride = (lane < 32) ? 32u : 0u;
    const unsigned bbase   = (lane < 32) ? (unsigned)l31
                                         : (unsigned)(CCHUNK + l31);
    const int toff = wv * (NTILE / 4);    // stagger waves' tile order
    const f32x16 zacc = {};

    for (int t = 0; t < NTILE; ++t) {
        const int tp = (t + toff) & (NTILE - 1);
        const uint2 bv = bfr[bbase + (unsigned)tp * bstride];
        const f32x16 acc =
            __builtin_amdgcn_mfma_f32_32x32x16_f16(a, mk_b(bv), zacc, 0, 0, 0);

        float c = 0.0f;
        #pragma unroll
        for (int q = 0; q < 4; ++q) {          // process 4 regs at a time
            float e0, e1, e2, e3;
            {
                const float s = fmaxf(acc[4*q+0], 0.0f);
                e0 = __uint_as_float((unsigned)(int)fmaf(
                    __uint_as_float((__float_as_uint(s) >> 1) + SQB), -FS, EXPA));
                const float s1 = fmaxf(acc[4*q+1], 0.0f);
                e1 = __uint_as_float((unsigned)(int)fmaf(
                    __uint_as_float((__float_as_uint(s1) >> 1) + SQB), -FS, EXPA));
                const float s2 = fmaxf(acc[4*q+2], 0.0f);
                e2 = __uint_as_float((unsigned)(int)fmaf(
                    __uint_as_float((__float_as_uint(s2) >> 1) + SQB), -FS, EXPA));
                const float s3 = fmaxf(acc[4*q+3], 0.0f);
                e3 = __uint_as_float((unsigned)(int)fmaf(
                    __uint_as_float((__float_as_uint(s3) >> 1) + SQB), -FS, EXPA));
            }
            rs[4*q+0] += e0; rs[4*q+1] += e1;
            rs[4*q+2] += e2; rs[4*q+3] += e3;
            c += (e0 + e1) + (e2 + e3);
        }
        // combine the two half-rows (lane l and l+32 hold the same column),
        // then a single 32-lane conflict-free ds_add
        c += __shfl_xor(c, 32);
        if (lane < 32)
            atomicAdd(&col_acc[tp * 32 + l31], c);
    }

    // row sums: rs[r] lives across 32 lanes (col index); reduce and commit
    #pragma unroll
    for (int r = 0; r < 16; ++r) {
        #pragma unroll
        for (int m = 1; m <= 16; m <<= 1)
            rs[r] += __shfl_xor(rs[r], m, 32);
    }
    if (l31 == 0) {                       // lanes 0 and 32
        const int half4 = (lane >> 5) << 2;
        float* rsum = row_sum + (size_t)n * M_PTS;
        #pragma unroll
        for (int r = 0; r < 16; ++r) {
            const int row = wrow0 + (r & 3) + ((r >> 2) << 3) + half4;
            atomicAdd(&rsum[row], rs[r]);  // 8 writers/addr (col-chunks)
        }
    }

    __syncthreads();
    for (int i = tid; i < CCHUNK; i += 256)
        atomicAdd(&col_sum[(size_t)n * K_PTS + cbase + i], col_acc[i]);
}

// ws: row_sum (N*M) then col_sum (N*K); equal counts -> single 1/(N*M) scale.
__global__ __launch_bounds__(256) void softhaus_finalize(
    const float* __restrict__ sums, float* __restrict__ out)
{
    const int total  = N_B * M_PTS + N_B * K_PTS;
    const int idx    = blockIdx.x * blockDim.x + threadIdx.x;
    const int stride = gridDim.x * blockDim.x;

    float acc = 0.0f;
    for (int i = idx; i < total; i += stride)
        acc -= __builtin_amdgcn_logf(sums[i]) * LN2;   // -log(v)

    #pragma unroll
    for (int off = 32; off > 0; off >>= 1)
        acc += __shfl_down(acc, off);

    __shared__ float wsum[4];
    const int lane = threadIdx.x & 63;
    const int wv   = threadIdx.x >> 6;
    if (lane == 0) wsum[wv] = acc;
    __syncthreads();
    if (threadIdx.x == 0) {
        float b = wsum[0] + wsum[1] + wsum[2] + wsum[3];
        atomicAdd(out, b * (1.0f / (N_B * M_PTS)));
    }
}

extern "C" void kernel_launch(void* const* d_in, const int* in_sizes, int n_in,
                              void* d_out, int out_size, void* d_ws, size_t ws_size,
                              hipStream_t stream) {
    const float* pred = (const float*)d_in[0];
    const float* gt   = (const float*)d_in[1];
    float* ws = (float*)d_ws;

    const size_t acc_bytes = (size_t)(N_B * M_PTS + N_B * K_PTS) * sizeof(float);
    hipMemsetAsync(d_ws, 0, acc_bytes, stream);
    hipMemsetAsync(d_out, 0, sizeof(float), stream);

    dim3 grid(M_PTS / 128, K_PTS / CCHUNK, N_B);   // 64 x 8 x 4 = 2048 blocks
    softhaus_pair<<<grid, 256, 0, stream>>>(pred, gt, ws, ws + (size_t)N_B * M_PTS);
    softhaus_finalize<<<64, 256, 0, stream>>>(ws, (float*)d_out);
}